// Round 2
// baseline (211.439 us; speedup 1.0000x reference)
//
#include <hip/hip_runtime.h>
#include <math.h>

#define NTH 256          // 4 waves per block
#define S_PER_WAVE 8     // samples per wave
#define TMB 32           // samples per block

__device__ __forceinline__ float waveSum(float v) {
#pragma unroll
  for (int off = 32; off; off >>= 1) v += __shfl_xor(v, off, 64);
  return v;
}

__device__ __forceinline__ float siluf(float x) { return x / (1.0f + expf(-x)); }

// Per-sample PL helper: given 5 selected exp-logits (uniform across wave), Z,
// each lane accumulates its share of the 120-permutation sum of
// prod_j 1/(Z - prefix). Lane p handles perms p and p+64.
__device__ __forceinline__ float permSum(const float se0, const float se1,
                                         const float se2, const float se3,
                                         const float se4, float Z, int lane) {
  float psum = 0.0f;
#pragma unroll
  for (int pp = 0; pp < 2; ++pp) {
    int p = lane + pp * 64;
    if (p < 120) {
      int rem = p;
      unsigned avail = 0x43210u;  // nibble i holds value i
      float c = 0.0f;
      float prod = Z;             // denominator for step 0
#pragma unroll
      for (int j = 0; j < 4; ++j) {
        const int fct = (j == 0) ? 24 : (j == 1) ? 6 : (j == 2) ? 2 : 1;
        int q = rem / fct; rem -= q * fct;
        int sh = q * 4;
        int dg = (avail >> sh) & 0xF;
        avail = (avail & ((1u << sh) - 1u)) | ((avail >> (sh + 4)) << sh);
        float ev = (dg == 0) ? se0 : (dg == 1) ? se1 : (dg == 2) ? se2
                 : (dg == 3) ? se3 : se4;
        c += ev;
        prod *= (Z - c);
      }
      psum += 1.0f / prod;
    }
  }
  return psum;
}

__global__ __launch_bounds__(NTH, 1)
void pcf_fused(const float* __restrict__ ua, const float* __restrict__ ub,
               const float* __restrict__ alog, const float* __restrict__ W1,
               const float* __restrict__ b1, const float* __restrict__ W2,
               const float* __restrict__ b2, const float* __restrict__ V1,
               const float* __restrict__ c1, const float* __restrict__ V2,
               const float* __restrict__ c2, const float* __restrict__ V3,
               const float* __restrict__ c3, float* __restrict__ out)
{
  // Per-wave private LDS slices (no __syncthreads needed for correctness;
  // same-wave LDS RAW is ordered via lgkmcnt).
  __shared__ float sA[4][2048];   // h (s*128+j) then z1 (s*256+k)
  __shared__ float sB[4][2048];   // ctx (s*64+c) then z2 (s*256+k)

  const int t    = threadIdx.x;
  const int lane = t & 63;
  const int wave = t >> 6;
  const int bbase = blockIdx.x * TMB + wave * S_PER_WAVE;

  float* A  = sA[wave];
  float* Bf = sB[wave];

  float lpA[S_PER_WAVE];   // alpha PL log-prob per sample (wave-uniform)

  //============ Phase A + H: alpha top-5, PL, and h rows ============
  {
    float la = alog[lane];
    float ea = expf(la);
    float Za = waveSum(ea);
    float2 b1v = *(const float2*)(b1 + 2 * lane);
#pragma unroll 1
    for (int s = 0; s < S_PER_WAVE; ++s) {
      int b = bbase + s;
      float u = ua[(size_t)b * 64 + lane];
      float g = -logf(-logf(fmaxf(u, 1e-10f)));
      float vcur = la + g;
      float sel_e[5]; int sel_i[5];
#pragma unroll
      for (int r = 0; r < 5; ++r) {
        float bv = vcur; int bi = lane;
#pragma unroll
        for (int off = 32; off; off >>= 1) {
          float ov = __shfl_xor(bv, off, 64);
          int   oi = __shfl_xor(bi, off, 64);
          if (ov > bv || (ov == bv && oi < bi)) { bv = ov; bi = oi; }
        }
        sel_i[r] = bi;                 // wave-uniform after butterfly
        sel_e[r] = __shfl(ea, bi, 64);
        if (lane == bi) vcur = -INFINITY;
      }
      float isSel = (vcur == -INFINITY) ? 1.0f : 0.0f;
      out[(size_t)b * 128 + lane] = isSel;                 // alpha config
      float sl = waveSum(isSel != 0.0f ? la : 0.0f);
      float S  = waveSum(permSum(sel_e[0], sel_e[1], sel_e[2], sel_e[3],
                                 sel_e[4], Za, lane));
      lpA[s] = sl + logf(S);

      // h[s] = silu(b1 + sum of 5 selected W1 rows); lane covers cols 2l,2l+1
      float h0 = b1v.x, h1 = b1v.y;
#pragma unroll
      for (int r = 0; r < 5; ++r) {
        float2 w = *(const float2*)(W1 + (size_t)sel_i[r] * 128 + 2 * lane);
        h0 += w.x; h1 += w.y;
      }
      float2 hv; hv.x = siluf(h0); hv.y = siluf(h1);
      *(float2*)&A[s * 128 + 2 * lane] = hv;
    }
  }
  __syncthreads();   // wave alignment only (L1 temporal locality on weights)

  //============ GEMM1: ctx[s][lane] = h[s] @ W2 + b2 ============
  {
    float acc[S_PER_WAVE];
    float bias = b2[lane];
#pragma unroll
    for (int s = 0; s < S_PER_WAVE; ++s) acc[s] = bias;
    const float* wp = W2 + lane;
#pragma unroll 4
    for (int m = 0; m < 32; ++m) {        // k = 4m..4m+3, K=128
      float w0 = wp[(4 * m + 0) * 64];
      float w1 = wp[(4 * m + 1) * 64];
      float w2 = wp[(4 * m + 2) * 64];
      float w3 = wp[(4 * m + 3) * 64];
#pragma unroll
      for (int s = 0; s < S_PER_WAVE; ++s) {
        float4 x = *(float4*)&A[s * 128 + 4 * m];
        acc[s] += x.x * w0 + x.y * w1 + x.z * w2 + x.w * w3;
      }
    }
#pragma unroll
    for (int s = 0; s < S_PER_WAVE; ++s) Bf[s * 64 + lane] = acc[s];
  }
  __syncthreads();

  //============ GEMM2: z1[s][4l..] = silu(ctx[s] @ V1[64:,:] + c1) ============
  {
    float4 acc[S_PER_WAVE];
    float4 cb = *(const float4*)(c1 + 4 * lane);
#pragma unroll
    for (int s = 0; s < S_PER_WAVE; ++s) acc[s] = cb;
    const float* wp = V1 + (size_t)64 * 256 + 4 * lane;
#pragma unroll 2
    for (int m = 0; m < 16; ++m) {        // K=64
      float4 w0 = *(const float4*)(wp + (4 * m + 0) * 256);
      float4 w1 = *(const float4*)(wp + (4 * m + 1) * 256);
      float4 w2 = *(const float4*)(wp + (4 * m + 2) * 256);
      float4 w3 = *(const float4*)(wp + (4 * m + 3) * 256);
#pragma unroll
      for (int s = 0; s < S_PER_WAVE; ++s) {
        float4 x = *(float4*)&Bf[s * 64 + 4 * m];
        acc[s].x += x.x * w0.x + x.y * w1.x + x.z * w2.x + x.w * w3.x;
        acc[s].y += x.x * w0.y + x.y * w1.y + x.z * w2.y + x.w * w3.y;
        acc[s].z += x.x * w0.z + x.y * w1.z + x.z * w2.z + x.w * w3.z;
        acc[s].w += x.x * w0.w + x.y * w1.w + x.z * w2.w + x.w * w3.w;
      }
    }
#pragma unroll
    for (int s = 0; s < S_PER_WAVE; ++s) {
      float4 o;
      o.x = siluf(acc[s].x); o.y = siluf(acc[s].y);
      o.z = siluf(acc[s].z); o.w = siluf(acc[s].w);
      *(float4*)&A[s * 256 + 4 * lane] = o;
    }
  }
  __syncthreads();

  //============ GEMM3: z2[s][4l..] = silu(z1[s] @ V2 + c2) ============
  {
    float4 acc[S_PER_WAVE];
    float4 cb = *(const float4*)(c2 + 4 * lane);
#pragma unroll
    for (int s = 0; s < S_PER_WAVE; ++s) acc[s] = cb;
    const float* wp = V2 + 4 * lane;
#pragma unroll 4
    for (int m = 0; m < 64; ++m) {        // K=256
      float4 w0 = *(const float4*)(wp + (4 * m + 0) * 256);
      float4 w1 = *(const float4*)(wp + (4 * m + 1) * 256);
      float4 w2 = *(const float4*)(wp + (4 * m + 2) * 256);
      float4 w3 = *(const float4*)(wp + (4 * m + 3) * 256);
#pragma unroll
      for (int s = 0; s < S_PER_WAVE; ++s) {
        float4 x = *(float4*)&A[s * 256 + 4 * m];
        acc[s].x += x.x * w0.x + x.y * w1.x + x.z * w2.x + x.w * w3.x;
        acc[s].y += x.x * w0.y + x.y * w1.y + x.z * w2.y + x.w * w3.y;
        acc[s].z += x.x * w0.z + x.y * w1.z + x.z * w2.z + x.w * w3.z;
        acc[s].w += x.x * w0.w + x.y * w1.w + x.z * w2.w + x.w * w3.w;
      }
    }
#pragma unroll
    for (int s = 0; s < S_PER_WAVE; ++s) {
      float4 o;
      o.x = siluf(acc[s].x); o.y = siluf(acc[s].y);
      o.z = siluf(acc[s].z); o.w = siluf(acc[s].w);
      *(float4*)&Bf[s * 256 + 4 * lane] = o;
    }
  }
  __syncthreads();

  //============ GEMM4: bl[s][lane] = z2[s] @ V3 + c3 ============
  float bl[S_PER_WAVE];
  {
    float bias = c3[lane];
#pragma unroll
    for (int s = 0; s < S_PER_WAVE; ++s) bl[s] = bias;
    const float* wp = V3 + lane;
#pragma unroll 4
    for (int m = 0; m < 64; ++m) {        // K=256
      float w0 = wp[(4 * m + 0) * 64];
      float w1 = wp[(4 * m + 1) * 64];
      float w2 = wp[(4 * m + 2) * 64];
      float w3 = wp[(4 * m + 3) * 64];
#pragma unroll
      for (int s = 0; s < S_PER_WAVE; ++s) {
        float4 x = *(float4*)&Bf[s * 256 + 4 * m];
        bl[s] += x.x * w0 + x.y * w1 + x.z * w2 + x.w * w3;
      }
    }
  }

  //============ Phase B: beta top-5 + PL + final log_probs ============
  {
#pragma unroll 1
    for (int s = 0; s < S_PER_WAVE; ++s) {
      int b = bbase + s;
      float blv = bl[s];
      float eb = expf(blv);
      float Zb = waveSum(eb);
      float u = ub[(size_t)b * 64 + lane];
      float g = -logf(-logf(fmaxf(u, 1e-10f)));
      float vcur = blv + g;
      float sel_e[5];
#pragma unroll
      for (int r = 0; r < 5; ++r) {
        float bv = vcur; int bi = lane;
#pragma unroll
        for (int off = 32; off; off >>= 1) {
          float ov = __shfl_xor(bv, off, 64);
          int   oi = __shfl_xor(bi, off, 64);
          if (ov > bv || (ov == bv && oi < bi)) { bv = ov; bi = oi; }
        }
        sel_e[r] = __shfl(eb, bi, 64);
        if (lane == bi) vcur = -INFINITY;
      }
      float isSel = (vcur == -INFINITY) ? 1.0f : 0.0f;
      out[(size_t)b * 128 + 64 + lane] = isSel;            // beta config
      float sl = waveSum(isSel != 0.0f ? blv : 0.0f);
      float S  = waveSum(permSum(sel_e[0], sel_e[1], sel_e[2], sel_e[3],
                                 sel_e[4], Zb, lane));
      if (lane == 0)
        out[(size_t)8192 * 128 + b] = lpA[s] + sl + logf(S);
    }
  }
}

extern "C" void kernel_launch(void* const* d_in, const int* in_sizes, int n_in,
                              void* d_out, int out_size, void* d_ws, size_t ws_size,
                              hipStream_t stream) {
  const float* ua   = (const float*)d_in[0];
  const float* ub   = (const float*)d_in[1];
  const float* alog = (const float*)d_in[2];
  const float* W1   = (const float*)d_in[3];
  const float* b1   = (const float*)d_in[4];
  const float* W2   = (const float*)d_in[5];
  const float* b2   = (const float*)d_in[6];
  const float* V1   = (const float*)d_in[7];
  const float* c1   = (const float*)d_in[8];
  const float* V2   = (const float*)d_in[9];
  const float* c2   = (const float*)d_in[10];
  const float* V3   = (const float*)d_in[11];
  const float* c3   = (const float*)d_in[12];
  float* out = (float*)d_out;

  pcf_fused<<<dim3(8192 / TMB), dim3(NTH), 0, stream>>>(
      ua, ub, alog, W1, b1, W2, b2, V1, c1, V2, c2, V3, c3, out);
}

// Round 3
// 150.086 us; speedup vs baseline: 1.4088x; 1.4088x over previous
//
#include <hip/hip_runtime.h>
#include <math.h>

#define NTH 256          // 4 waves per block
#define S_PER_WAVE 2     // samples per wave
#define TMB 8            // samples per block (4 waves * 2)

__device__ __forceinline__ float waveSum(float v) {
#pragma unroll
  for (int off = 32; off; off >>= 1) v += __shfl_xor(v, off, 64);
  return v;
}

__device__ __forceinline__ float siluf(float x) { return x / (1.0f + expf(-x)); }

// Per-sample PL helper: given 5 selected exp-logits (uniform across wave), Z,
// each lane accumulates its share of the 120-permutation sum of
// prod_j 1/(Z - prefix). Lane p handles perms p and p+64.
__device__ __forceinline__ float permSum(const float se0, const float se1,
                                         const float se2, const float se3,
                                         const float se4, float Z, int lane) {
  float psum = 0.0f;
#pragma unroll
  for (int pp = 0; pp < 2; ++pp) {
    int p = lane + pp * 64;
    if (p < 120) {
      int rem = p;
      unsigned avail = 0x43210u;  // nibble i holds value i
      float c = 0.0f;
      float prod = Z;             // denominator for step 0
#pragma unroll
      for (int j = 0; j < 4; ++j) {
        const int fct = (j == 0) ? 24 : (j == 1) ? 6 : (j == 2) ? 2 : 1;
        int q = rem / fct; rem -= q * fct;
        int sh = q * 4;
        int dg = (avail >> sh) & 0xF;
        avail = (avail & ((1u << sh) - 1u)) | ((avail >> (sh + 4)) << sh);
        float ev = (dg == 0) ? se0 : (dg == 1) ? se1 : (dg == 2) ? se2
                 : (dg == 3) ? se3 : se4;
        c += ev;
        prod *= (Z - c);
      }
      psum += 1.0f / prod;
    }
  }
  return psum;
}

__global__ __launch_bounds__(NTH, 4)
void pcf_fused(const float* __restrict__ ua, const float* __restrict__ ub,
               const float* __restrict__ alog, const float* __restrict__ W1,
               const float* __restrict__ b1, const float* __restrict__ W2,
               const float* __restrict__ b2, const float* __restrict__ V1,
               const float* __restrict__ c1, const float* __restrict__ V2,
               const float* __restrict__ c2, const float* __restrict__ V3,
               const float* __restrict__ c3, float* __restrict__ out)
{
  // Per-wave private LDS slices (no cross-wave sharing; same-wave LDS RAW
  // ordered via lgkmcnt). 2 KB per wave per buffer -> 16 KB per block.
  __shared__ float sA[4][S_PER_WAVE * 256];   // h (s*128+j) then z1 (s*256+k)
  __shared__ float sB[4][S_PER_WAVE * 256];   // ctx (s*64+c) then z2 (s*256+k)

  const int t    = threadIdx.x;
  const int lane = t & 63;
  const int wave = t >> 6;
  const int bbase = blockIdx.x * TMB + wave * S_PER_WAVE;

  float* A  = sA[wave];
  float* Bf = sB[wave];

  float lpA[S_PER_WAVE];   // alpha PL log-prob per sample (wave-uniform)

  //============ Phase A + H: alpha top-5, PL, and h rows ============
  {
    float la = alog[lane];
    float ea = expf(la);
    float Za = waveSum(ea);
    float2 b1v = *(const float2*)(b1 + 2 * lane);
#pragma unroll
    for (int s = 0; s < S_PER_WAVE; ++s) {
      int b = bbase + s;
      float u = ua[(size_t)b * 64 + lane];
      float g = -logf(-logf(fmaxf(u, 1e-10f)));
      float vcur = la + g;
      float sel_e[5]; int sel_i[5];
#pragma unroll
      for (int r = 0; r < 5; ++r) {
        float bv = vcur; int bi = lane;
#pragma unroll
        for (int off = 32; off; off >>= 1) {
          float ov = __shfl_xor(bv, off, 64);
          int   oi = __shfl_xor(bi, off, 64);
          if (ov > bv || (ov == bv && oi < bi)) { bv = ov; bi = oi; }
        }
        sel_i[r] = bi;                 // wave-uniform after butterfly
        sel_e[r] = __shfl(ea, bi, 64);
        if (lane == bi) vcur = -INFINITY;
      }
      float isSel = (vcur == -INFINITY) ? 1.0f : 0.0f;
      out[(size_t)b * 128 + lane] = isSel;                 // alpha config
      float sl = waveSum(isSel != 0.0f ? la : 0.0f);
      float S  = waveSum(permSum(sel_e[0], sel_e[1], sel_e[2], sel_e[3],
                                 sel_e[4], Za, lane));
      lpA[s] = sl + logf(S);

      // h[s] = silu(b1 + sum of 5 selected W1 rows); lane covers cols 2l,2l+1
      float h0 = b1v.x, h1 = b1v.y;
#pragma unroll
      for (int r = 0; r < 5; ++r) {
        float2 w = *(const float2*)(W1 + (size_t)sel_i[r] * 128 + 2 * lane);
        h0 += w.x; h1 += w.y;
      }
      float2 hv; hv.x = siluf(h0); hv.y = siluf(h1);
      *(float2*)&A[s * 128 + 2 * lane] = hv;
    }
  }
  __syncthreads();   // wave alignment only (L1 temporal locality on weights)

  //============ GEMM1: ctx[s][lane] = h[s] @ W2 + b2 ============
  {
    float acc[S_PER_WAVE];
    float bias = b2[lane];
#pragma unroll
    for (int s = 0; s < S_PER_WAVE; ++s) acc[s] = bias;
    const float* wp = W2 + lane;
#pragma unroll 4
    for (int m = 0; m < 32; ++m) {        // k = 4m..4m+3, K=128
      float w0 = wp[(4 * m + 0) * 64];
      float w1 = wp[(4 * m + 1) * 64];
      float w2 = wp[(4 * m + 2) * 64];
      float w3 = wp[(4 * m + 3) * 64];
#pragma unroll
      for (int s = 0; s < S_PER_WAVE; ++s) {
        float4 x = *(float4*)&A[s * 128 + 4 * m];
        acc[s] += x.x * w0 + x.y * w1 + x.z * w2 + x.w * w3;
      }
    }
#pragma unroll
    for (int s = 0; s < S_PER_WAVE; ++s) Bf[s * 64 + lane] = acc[s];
  }
  __syncthreads();

  //============ GEMM2: z1[s][4l..] = silu(ctx[s] @ V1[64:,:] + c1) ============
  {
    float4 acc[S_PER_WAVE];
    float4 cb = *(const float4*)(c1 + 4 * lane);
#pragma unroll
    for (int s = 0; s < S_PER_WAVE; ++s) acc[s] = cb;
    const float* wp = V1 + (size_t)64 * 256 + 4 * lane;
#pragma unroll 2
    for (int m = 0; m < 16; ++m) {        // K=64
      float4 w0 = *(const float4*)(wp + (4 * m + 0) * 256);
      float4 w1 = *(const float4*)(wp + (4 * m + 1) * 256);
      float4 w2 = *(const float4*)(wp + (4 * m + 2) * 256);
      float4 w3 = *(const float4*)(wp + (4 * m + 3) * 256);
#pragma unroll
      for (int s = 0; s < S_PER_WAVE; ++s) {
        float4 x = *(float4*)&Bf[s * 64 + 4 * m];
        acc[s].x += x.x * w0.x + x.y * w1.x + x.z * w2.x + x.w * w3.x;
        acc[s].y += x.x * w0.y + x.y * w1.y + x.z * w2.y + x.w * w3.y;
        acc[s].z += x.x * w0.z + x.y * w1.z + x.z * w2.z + x.w * w3.z;
        acc[s].w += x.x * w0.w + x.y * w1.w + x.z * w2.w + x.w * w3.w;
      }
    }
#pragma unroll
    for (int s = 0; s < S_PER_WAVE; ++s) {
      float4 o;
      o.x = siluf(acc[s].x); o.y = siluf(acc[s].y);
      o.z = siluf(acc[s].z); o.w = siluf(acc[s].w);
      *(float4*)&A[s * 256 + 4 * lane] = o;
    }
  }
  __syncthreads();

  //============ GEMM3: z2[s][4l..] = silu(z1[s] @ V2 + c2) ============
  {
    float4 acc[S_PER_WAVE];
    float4 cb = *(const float4*)(c2 + 4 * lane);
#pragma unroll
    for (int s = 0; s < S_PER_WAVE; ++s) acc[s] = cb;
    const float* wp = V2 + 4 * lane;
#pragma unroll 4
    for (int m = 0; m < 64; ++m) {        // K=256
      float4 w0 = *(const float4*)(wp + (4 * m + 0) * 256);
      float4 w1 = *(const float4*)(wp + (4 * m + 1) * 256);
      float4 w2 = *(const float4*)(wp + (4 * m + 2) * 256);
      float4 w3 = *(const float4*)(wp + (4 * m + 3) * 256);
#pragma unroll
      for (int s = 0; s < S_PER_WAVE; ++s) {
        float4 x = *(float4*)&A[s * 256 + 4 * m];
        acc[s].x += x.x * w0.x + x.y * w1.x + x.z * w2.x + x.w * w3.x;
        acc[s].y += x.x * w0.y + x.y * w1.y + x.z * w2.y + x.w * w3.y;
        acc[s].z += x.x * w0.z + x.y * w1.z + x.z * w2.z + x.w * w3.z;
        acc[s].w += x.x * w0.w + x.y * w1.w + x.z * w2.w + x.w * w3.w;
      }
    }
#pragma unroll
    for (int s = 0; s < S_PER_WAVE; ++s) {
      float4 o;
      o.x = siluf(acc[s].x); o.y = siluf(acc[s].y);
      o.z = siluf(acc[s].z); o.w = siluf(acc[s].w);
      *(float4*)&Bf[s * 256 + 4 * lane] = o;
    }
  }
  __syncthreads();

  //============ GEMM4: bl[s][lane] = z2[s] @ V3 + c3 ============
  float bl[S_PER_WAVE];
  {
    float bias = c3[lane];
#pragma unroll
    for (int s = 0; s < S_PER_WAVE; ++s) bl[s] = bias;
    const float* wp = V3 + lane;
#pragma unroll 4
    for (int m = 0; m < 64; ++m) {        // K=256
      float w0 = wp[(4 * m + 0) * 64];
      float w1 = wp[(4 * m + 1) * 64];
      float w2 = wp[(4 * m + 2) * 64];
      float w3 = wp[(4 * m + 3) * 64];
#pragma unroll
      for (int s = 0; s < S_PER_WAVE; ++s) {
        float4 x = *(float4*)&Bf[s * 256 + 4 * m];
        bl[s] += x.x * w0 + x.y * w1 + x.z * w2 + x.w * w3;
      }
    }
  }

  //============ Phase B: beta top-5 + PL + final log_probs ============
  {
#pragma unroll
    for (int s = 0; s < S_PER_WAVE; ++s) {
      int b = bbase + s;
      float blv = bl[s];
      float eb = expf(blv);
      float Zb = waveSum(eb);
      float u = ub[(size_t)b * 64 + lane];
      float g = -logf(-logf(fmaxf(u, 1e-10f)));
      float vcur = blv + g;
      float sel_e[5];
#pragma unroll
      for (int r = 0; r < 5; ++r) {
        float bv = vcur; int bi = lane;
#pragma unroll
        for (int off = 32; off; off >>= 1) {
          float ov = __shfl_xor(bv, off, 64);
          int   oi = __shfl_xor(bi, off, 64);
          if (ov > bv || (ov == bv && oi < bi)) { bv = ov; bi = oi; }
        }
        sel_e[r] = __shfl(eb, bi, 64);
        if (lane == bi) vcur = -INFINITY;
      }
      float isSel = (vcur == -INFINITY) ? 1.0f : 0.0f;
      out[(size_t)b * 128 + 64 + lane] = isSel;            // beta config
      float sl = waveSum(isSel != 0.0f ? blv : 0.0f);
      float S  = waveSum(permSum(sel_e[0], sel_e[1], sel_e[2], sel_e[3],
                                 sel_e[4], Zb, lane));
      if (lane == 0)
        out[(size_t)8192 * 128 + b] = lpA[s] + sl + logf(S);
    }
  }
}

extern "C" void kernel_launch(void* const* d_in, const int* in_sizes, int n_in,
                              void* d_out, int out_size, void* d_ws, size_t ws_size,
                              hipStream_t stream) {
  const float* ua   = (const float*)d_in[0];
  const float* ub   = (const float*)d_in[1];
  const float* alog = (const float*)d_in[2];
  const float* W1   = (const float*)d_in[3];
  const float* b1   = (const float*)d_in[4];
  const float* W2   = (const float*)d_in[5];
  const float* b2   = (const float*)d_in[6];
  const float* V1   = (const float*)d_in[7];
  const float* c1   = (const float*)d_in[8];
  const float* V2   = (const float*)d_in[9];
  const float* c2   = (const float*)d_in[10];
  const float* V3   = (const float*)d_in[11];
  const float* c3   = (const float*)d_in[12];
  float* out = (float*)d_out;

  pcf_fused<<<dim3(8192 / TMB), dim3(NTH), 0, stream>>>(
      ua, ub, alog, W1, b1, W2, b2, V1, c1, V2, c2, V3, c3, out);
}